// Round 15
// baseline (43.206 us; speedup 1.0000x reference)
//
#include <hip/hip_runtime.h>

typedef __bf16 bf16x8 __attribute__((ext_vector_type(8)));
typedef float f32x16 __attribute__((ext_vector_type(16)));
typedef float f32x4 __attribute__((ext_vector_type(4)));

#define S_TOTAL 8192
#define DIM 256
#define BK 16
#define NSP 32

// R15: TLP experiment done right. Block = (batch, sp, jq, ih): 128x64 partial
// slice over kc=256. 256 thr = 4 waves (2x2; wave tile 64x32, 32 AGPR acc,
// ~72 total regs). 2-buf f32 LDS (A[16][128] 8KB + B[16][64] 4KB per buf =
// 24KB) -> 6 blocks/CU legal. Grid = 2048 blocks = 32 waves/CU dispatched
// (prior rounds: <=16). Staging pure global_load_lds DMA, uniform 3
// instrs/wave/tile, counted vmcnt. The 8 slice-mates of each (batch,sp)
// share their input chunk through one XCD's L2 (stride-8 swizzle; dedup
// mechanism FETCH-verified in R11/R13).
__global__ __launch_bounds__(256, 6) void opm_partial(
    const float* __restrict__ A, const float* __restrict__ Bm,
    __bf16* __restrict__ dstbf, float* __restrict__ dstf32,
    int nsp, int kc, float scale)
{
    __shared__ float lA[2][BK * 128];   // 2 x 8 KB
    __shared__ float lB[2][BK * 64];    // 2 x 4 KB

    const int tid = threadIdx.x;
    const int w   = tid >> 6;            // 0..3
    const int l   = tid & 63;

    // swizzle: bid = x + 8*(mate + 8*gx); mates (jq,ih) of group g=gx*8+x all on XCD x
    const int bid  = blockIdx.x;
    const int x    = bid & 7;
    const int r    = bid >> 3;
    const int mate = r & 7;
    const int gx   = r >> 3;
    const int jq   = mate >> 1;
    const int ih   = mate & 1;
    const int g    = gx * 8 + x;
    const int batch = g / nsp;
    const int sp    = g % nsp;

    const long long base = (long long)batch * S_TOTAL * DIM;
    const int s0 = sp * kc;
    const int wr = w >> 1, wc = w & 1;   // 2x2 wave grid
    const int lane31 = l & 31;
    const int hi = l >> 5;
    const int niter = kc / BK;

    f32x16 acc[2] = {};                  // 32 AGPR

    // DMA per tile per wave: 2 A instrs (2 rows of 128 f32 each) + 1 B instr
    // (4 rows of 64 f32). Uniform 3 VMEM instrs/wave.
    auto issue = [&](int it) {
        const int b2 = it & 1;
        const long long sb = (long long)(s0 + it * BK);
        #pragma unroll
        for (int q = 0; q < 2; ++q) {
            __builtin_amdgcn_global_load_lds(
                (const __attribute__((address_space(1))) unsigned int*)(
                    A + base + (sb + 4 * w + 2 * q + (l >> 5)) * DIM + ih * 128 + 4 * (l & 31)),
                (__attribute__((address_space(3))) unsigned int*)&lA[b2][(4 * w + 2 * q) * 128], 16, 0, 0);
        }
        __builtin_amdgcn_global_load_lds(
            (const __attribute__((address_space(1))) unsigned int*)(
                Bm + base + (sb + 4 * w + (l >> 4)) * DIM + jq * 64 + 4 * (l & 15)),
            (__attribute__((address_space(3))) unsigned int*)&lB[b2][4 * w * 64], 16, 0, 0);
    };

    auto compute = [&](int b2) {
        bf16x8 af[2], bfv;
        #pragma unroll
        for (int mi = 0; mi < 2; ++mi)
            #pragma unroll
            for (int e = 0; e < 8; ++e)
                af[mi][e] = (__bf16)lA[b2][(hi * 8 + e) * 128 + wr * 64 + mi * 32 + lane31];
        #pragma unroll
        for (int e = 0; e < 8; ++e)
            bfv[e] = (__bf16)lB[b2][(hi * 8 + e) * 64 + wc * 32 + lane31];
        acc[0] = __builtin_amdgcn_mfma_f32_32x32x16_bf16(af[0], bfv, acc[0], 0, 0, 0);
        acc[1] = __builtin_amdgcn_mfma_f32_32x32x16_bf16(af[1], bfv, acc[1], 0, 0, 0);
    };

    issue(0);
    issue(1);

    for (int it = 0; it < niter; ++it) {
        if (it == 0) asm volatile("s_waitcnt vmcnt(3)" ::: "memory");  // T1's 3 outstanding
        else         asm volatile("s_waitcnt vmcnt(0)" ::: "memory");
        __builtin_amdgcn_s_barrier();            // T_it landed for all waves
        if (it >= 1 && it + 1 < niter) issue(it + 1);  // buf consumed pre-barrier
        compute(it & 1);
    }

    // ---- epilogue: 128x64 slice ----
    if (dstf32) {
        float* o = dstf32 + (long long)batch * (256 * 256) + ih * 128 * 256 + jq * 64;
        #pragma unroll
        for (int mi = 0; mi < 2; ++mi)
        #pragma unroll
        for (int q = 0; q < 16; ++q) {
            const int row = (q & 3) + 8 * (q >> 2) + 4 * hi;
            o[(wr * 64 + mi * 32 + row) * 256 + wc * 32 + lane31] = acc[mi][q] * scale;
        }
    } else {
        // band-repack through dead LDS, then coalesced bf16x8 stores (contig tile)
        __bf16* o = dstbf + (long long)((batch * nsp + sp) * 8 + mate) * 8192;
        __bf16* ebuf = (__bf16*)&lA[0][0];   // 16 KB: 128 rows x 64 cols
        __syncthreads();
        #pragma unroll
        for (int mi = 0; mi < 2; ++mi)
        #pragma unroll
        for (int q = 0; q < 16; ++q) {
            const int row = wr * 64 + mi * 32 + (q & 3) + 8 * (q >> 2) + 4 * hi;
            ebuf[row * 64 + wc * 32 + lane31] = (__bf16)(acc[mi][q] * scale);
        }
        __syncthreads();
        #pragma unroll
        for (int h = 0; h < 4; ++h) {
            const int G = tid + h * 256;         // 1024 bf16x8 groups
            *(bf16x8*)&o[G * 8] = *(const bf16x8*)&ebuf[G * 8];
        }
    }
}

// Sum NSP=32 bf16 partials, scale by 1/8192. Fully unrolled (R10-proven).
// ws tile t = ((batch*NSP+sp)*8 + jq*2 + ih) is a contiguous [128][64] slice.
__global__ __launch_bounds__(256) void opm_reduce32(
    const __bf16* __restrict__ ws, float* __restrict__ out)
{
    const int idx = blockIdx.x * 256 + threadIdx.x;  // 65536 bf16x8 groups
    const int batch = idx >> 13;
    const int gg  = idx & 8191;
    const int i   = gg >> 5;                         // output row 0..255
    const int jc  = gg & 31;                         // col-group 0..31
    const int jq  = jc >> 3;
    const int ihh = i >> 7;
    const int ir  = i & 127;
    const int c8  = (jc & 7) * 8;

    const bf16x8* p = (const bf16x8*)(ws
        + ((long long)(batch * NSP) * 8 + jq * 2 + ihh) * 8192 + ir * 64 + c8);
    // sp stride = 8 tiles x 1024 groups = 8192 bf16x8 groups
    bf16x8 v[NSP];
    #pragma unroll
    for (int sp = 0; sp < NSP; ++sp) v[sp] = p[sp * 8192];

    float sacc[8] = {0.f, 0.f, 0.f, 0.f, 0.f, 0.f, 0.f, 0.f};
    #pragma unroll
    for (int sp = 0; sp < NSP; ++sp)
        #pragma unroll
        for (int e = 0; e < 8; ++e) sacc[e] += (float)v[sp][e];

    f32x4 lo = { sacc[0], sacc[1], sacc[2], sacc[3] };
    f32x4 hiv = { sacc[4], sacc[5], sacc[6], sacc[7] };
    lo  *= (1.0f / 8192.0f);
    hiv *= (1.0f / 8192.0f);
    ((f32x4*)out)[idx * 2]     = lo;
    ((f32x4*)out)[idx * 2 + 1] = hiv;
}

extern "C" void kernel_launch(void* const* d_in, const int* in_sizes, int n_in,
                              void* d_out, int out_size, void* d_ws, size_t ws_size,
                              hipStream_t stream)
{
    (void)in_sizes; (void)n_in; (void)out_size;
    const float* A  = (const float*)d_in[0];
    const float* Bm = (const float*)d_in[1];
    float* out = (float*)d_out;

    if (ws_size >= (size_t)8 * NSP * 8 * 8192 * sizeof(__bf16)) {   // 32 MB
        opm_partial<<<8 * NSP * 8, 256, 0, stream>>>(A, Bm, (__bf16*)d_ws, nullptr,
                                                     NSP, S_TOTAL / NSP, 1.0f);
        opm_reduce32<<<256, 256, 0, stream>>>((const __bf16*)d_ws, out);
    } else {
        // tiny-ws fallback: 64 blocks (8 batch x 8 mates), full K, f32 direct
        opm_partial<<<64, 256, 0, stream>>>(A, Bm, nullptr, out, 1, S_TOTAL, 1.0f / 8192.0f);
    }
}

// Round 16
// 34.036 us; speedup vs baseline: 1.2694x; 1.2694x over previous
//
#include <hip/hip_runtime.h>

typedef __bf16 bf16x8 __attribute__((ext_vector_type(8)));
typedef float f32x16 __attribute__((ext_vector_type(16)));
typedef float f32x4 __attribute__((ext_vector_type(4)));

#define S_TOTAL 8192
#define DIM 256
#define BK 16
#define NSP 16

// R16: R11's proven rate structure + half the ws. Block = (batch, sp, ih, jh):
// 128x128 partial tile over kc=512. 512 thr = 8 waves (2x4; wave tile 64x32,
// 32 AGPR acc). Staging: pure global_load_lds DMA, uniform 2 instrs/wave/tile
// (A rows {2w,2w+1} ih-half, B rows {2w,2w+1} jh-half; both 2x512B segments
// per instr — R11's pattern quality for BOTH matrices, unlike R13). 3-buf
// 16KB bufs (48KB LDS), depth-2 prefetch, counted vmcnt(2), 2 blocks/CU.
// The 4 mates of each (batch,sp) share input chunks via one XCD's L2
// (stride-8 swizzle; dedup FETCH-verified R11/R13/R15). ws = 16 MB.
__global__ __launch_bounds__(512, 4) void opm_partial(
    const float* __restrict__ A, const float* __restrict__ Bm,
    __bf16* __restrict__ dstbf, float* __restrict__ dstf32,
    int nsp, int kc, float scale)
{
    __shared__ float lds[3 * 4096];      // 48 KB: buf b = lds+b*4096 (A 2048 | B 2048)

    const int tid = threadIdx.x;
    const int w   = tid >> 6;            // 0..7
    const int l   = tid & 63;

    // swizzle: bid = x + 8*(gx*4 + mate); group g = gx*8 + x, 4 mates per g on XCD x
    const int bid  = blockIdx.x;
    const int x    = bid & 7;
    const int r    = bid >> 3;
    const int mate = r & 3;
    const int gx   = r >> 2;
    const int ih   = mate >> 1;
    const int jh   = mate & 1;
    const int g    = gx * 8 + x;
    const int batch = g / nsp;
    const int sp    = g % nsp;

    const long long base = (long long)batch * S_TOTAL * DIM;
    const int s0 = sp * kc;
    const int wr = w >> 2, wc = w & 3;   // 2x4 wave grid
    const int lane31 = l & 31;
    const int hi = l >> 5;
    const int niter = kc / BK;           // 32 (split path)

    f32x16 acc[2] = {};                  // 32 AGPR

    // 2 DMA instrs/wave/tile: A rows {2w,2w+1} (ih-half, 512B each) and
    // B rows {2w,2w+1} (jh-half). Lanes 0-31 -> row 2w, 32-63 -> row 2w+1.
    auto issue = [&](int it) {
        float* buf = &lds[(it % 3) * 4096];
        const long long srow = base + (long long)(s0 + it * BK + 2 * w + (l >> 5)) * DIM + 4 * (l & 31);
        __builtin_amdgcn_global_load_lds(
            (const __attribute__((address_space(1))) unsigned int*)(A + srow + ih * 128),
            (__attribute__((address_space(3))) unsigned int*)(buf + 2 * w * 128), 16, 0, 0);
        __builtin_amdgcn_global_load_lds(
            (const __attribute__((address_space(1))) unsigned int*)(Bm + srow + jh * 128),
            (__attribute__((address_space(3))) unsigned int*)(buf + 2048 + 2 * w * 128), 16, 0, 0);
    };

    auto compute = [&](int b3) {
        const float* bufA = &lds[b3 * 4096];
        const float* bufB = bufA + 2048;
        bf16x8 af[2], bfv;
        #pragma unroll
        for (int mi = 0; mi < 2; ++mi)
            #pragma unroll
            for (int e = 0; e < 8; ++e)
                af[mi][e] = (__bf16)bufA[(hi * 8 + e) * 128 + wr * 64 + mi * 32 + lane31];
        #pragma unroll
        for (int e = 0; e < 8; ++e)
            bfv[e] = (__bf16)bufB[(hi * 8 + e) * 128 + wc * 32 + lane31];
        acc[0] = __builtin_amdgcn_mfma_f32_32x32x16_bf16(af[0], bfv, acc[0], 0, 0, 0);
        acc[1] = __builtin_amdgcn_mfma_f32_32x32x16_bf16(af[1], bfv, acc[1], 0, 0, 0);
    };

    issue(0);
    issue(1);

    for (int it = 0; it < niter; ++it) {
        if (it + 1 < niter) asm volatile("s_waitcnt vmcnt(2)" ::: "memory");  // T_it done, T_{it+1} flying
        else                asm volatile("s_waitcnt vmcnt(0)" ::: "memory");
        __builtin_amdgcn_s_barrier();            // T_it landed for all waves
        if (it + 2 < niter) issue(it + 2);       // buf (it+2)%3 == (it-1)%3: consumed
        compute(it % 3);
    }

    // ---- epilogue: 128x128 tile ----
    if (dstf32) {
        float* o = dstf32 + (long long)batch * (256 * 256) + (ih * 128) * 256 + jh * 128;
        #pragma unroll
        for (int mi = 0; mi < 2; ++mi)
        #pragma unroll
        for (int q = 0; q < 16; ++q) {
            const int row = (q & 3) + 8 * (q >> 2) + 4 * hi;
            o[(wr * 64 + mi * 32 + row) * 256 + wc * 32 + lane31] = acc[mi][q] * scale;
        }
    } else {
        // band-repack (2 bands of 64 rows) through dead LDS -> coalesced bf16x8
        __bf16* o = dstbf + (long long)((batch * nsp + sp) * 4 + ih * 2 + jh) * 16384;
        __bf16* ebuf = (__bf16*)&lds[0];     // 16 KB: 64 rows x 128 cols
        #pragma unroll
        for (int band = 0; band < 2; ++band) {
            __syncthreads();
            if (wr == band) {
                #pragma unroll
                for (int mi = 0; mi < 2; ++mi)
                #pragma unroll
                for (int q = 0; q < 16; ++q) {
                    const int lr = mi * 32 + (q & 3) + 8 * (q >> 2) + 4 * hi;
                    ebuf[lr * 128 + wc * 32 + lane31] = (__bf16)(acc[mi][q] * scale);
                }
            }
            __syncthreads();
            #pragma unroll
            for (int h = 0; h < 2; ++h) {
                const int G = tid + h * 512;     // 1024 bf16x8 groups per band
                *(bf16x8*)&o[band * 8192 + G * 8] = *(const bf16x8*)&ebuf[G * 8];
            }
        }
    }
}

// Sum NSP=16 bf16 partials, scale by 1/8192. Fully unrolled (R10-proven).
// ws tile t = ((batch*NSP+sp)*4 + ih*2 + jh): contiguous [128][128] bf16.
__global__ __launch_bounds__(256) void opm_reduce16(
    const __bf16* __restrict__ ws, float* __restrict__ out)
{
    const int idx = blockIdx.x * 256 + threadIdx.x;  // 65536 output bf16x8-groups
    const int batch = idx >> 13;
    const int gg  = idx & 8191;
    const int i   = gg >> 5;                         // 0..255
    const int jg  = gg & 31;                         // col-group (8 wide)
    const int ih  = i >> 7, ir = i & 127;
    const int jh  = jg >> 4, jc = jg & 15;

    const bf16x8* p = (const bf16x8*)ws
        + ((long long)(batch * NSP) * 4 + ih * 2 + jh) * 2048 + ir * 16 + jc;
    // sp stride = 4 tiles x 2048 groups = 8192 groups
    bf16x8 v[NSP];
    #pragma unroll
    for (int sp = 0; sp < NSP; ++sp) v[sp] = p[sp * 8192];

    float sacc[8] = {0.f, 0.f, 0.f, 0.f, 0.f, 0.f, 0.f, 0.f};
    #pragma unroll
    for (int sp = 0; sp < NSP; ++sp)
        #pragma unroll
        for (int e = 0; e < 8; ++e) sacc[e] += (float)v[sp][e];

    f32x4 lo = { sacc[0], sacc[1], sacc[2], sacc[3] };
    f32x4 hiv = { sacc[4], sacc[5], sacc[6], sacc[7] };
    lo  *= (1.0f / 8192.0f);
    hiv *= (1.0f / 8192.0f);
    ((f32x4*)out)[idx * 2]     = lo;
    ((f32x4*)out)[idx * 2 + 1] = hiv;
}

extern "C" void kernel_launch(void* const* d_in, const int* in_sizes, int n_in,
                              void* d_out, int out_size, void* d_ws, size_t ws_size,
                              hipStream_t stream)
{
    (void)in_sizes; (void)n_in; (void)out_size;
    const float* A  = (const float*)d_in[0];
    const float* Bm = (const float*)d_in[1];
    float* out = (float*)d_out;

    if (ws_size >= (size_t)8 * NSP * 4 * 16384 * sizeof(__bf16)) {   // 16 MB
        opm_partial<<<8 * NSP * 4, 512, 0, stream>>>(A, Bm, (__bf16*)d_ws, nullptr,
                                                     NSP, S_TOTAL / NSP, 1.0f);
        opm_reduce16<<<256, 256, 0, stream>>>((const __bf16*)d_ws, out);
    } else {
        // tiny-ws fallback: 32 blocks (8 batch x 4 mates), full K, f32 direct
        opm_partial<<<32, 512, 0, stream>>>(A, Bm, nullptr, out, 1, S_TOTAL, 1.0f / 8192.0f);
    }
}